// Round 17
// baseline (26.379 us; speedup 1.0000x reference)
//
#include <hip/hip_runtime.h>
#include <hip/hip_bf16.h>

// Problem: B=24, L=512, D=64, H=64
//   h = gelu(x @ W + b); S = h_i h_j^T per pair; scores = logsumexp(S).
// 300 unique (i<=j) pairs, mirrored at the end.
//
// R17 = R15 (25.5us; setprio reverted - null) + finish fused into pair
// WITHOUT R13's __threadfence toxin (device-scope release = L2 cache
// maintenance x1200 blocks = +24us). Ordering instead via atomic return
// value: consuming the sums-atomicAdd result forces s_waitcnt vmcnt(0)
// (completion at the L2 coherence point) before the cnt-atomicAdd is
// issued; the 4th cnt observer therefore sees all four sums-adds.
// 2 dispatches. encode (blocks 0-2) zeroes the 600-u32 scratch each
// call (replay-safe; stream-ordered before pair).

typedef unsigned short u16;
typedef unsigned int u32;
typedef __attribute__((ext_vector_type(8))) short bf16x8;
typedef __attribute__((ext_vector_type(4))) float f32x4;
typedef __attribute__((ext_vector_type(16))) float f32x16;

static __device__ __forceinline__ u16 bf16bits(float f) {
  __hip_bfloat16 h = __float2bfloat16(f);
  return *reinterpret_cast<u16*>(&h);
}

// Schraudolph fast e^x (log2e folded into the multiplier):
// e^x ~= as_float((int)(x*log2e*2^23 + (127*2^23 - 254615))).
// Valid |x| < 87; rel err <= 3.04%  ->  <=0.03 absolute on log-scores.
static __device__ __forceinline__ float fast_exp(float x) {
  int i = (int)fmaf(x, 12102203.0f, 1065098601.0f);
  return __int_as_float(i);
}

// ---------------- encoder: h = gelu(x@W+b) via MFMA -----------------------
// Also zeroes the sums/cnt scratch (blocks 0-2; 600 u32), which pair
// consumes strictly after this kernel completes (stream order).
__global__ __launch_bounds__(256) void encode_kernel(
    const float* __restrict__ x, const float* __restrict__ W,
    const float* __restrict__ bias, u16* __restrict__ hb,
    u32* __restrict__ sums_cnt) {
  if (blockIdx.x < 3) {
    int t = blockIdx.x * 256 + threadIdx.x;
    if (t < 600) sums_cnt[t] = 0u;
  }

  int lane = threadIdx.x & 63;
  int wid = threadIdx.x >> 6;
  int row0 = (blockIdx.x * 4 + wid) * 16;      // 12288 rows / 16 = 768 waves
  int r = lane & 15;
  int kg = lane >> 4;

  bf16x8 xa[2];
#pragma unroll
  for (int kh = 0; kh < 2; ++kh) {
    const float* xp = x + (size_t)(row0 + r) * 64 + kh * 32 + kg * 8;
    bf16x8 v;
#pragma unroll
    for (int e = 0; e < 8; ++e) v[e] = (short)bf16bits(xp[e]);
    xa[kh] = v;
  }

  bf16x8 wf[4][2];
#pragma unroll
  for (int nb = 0; nb < 4; ++nb)
#pragma unroll
    for (int kh = 0; kh < 2; ++kh) {
      bf16x8 v;
#pragma unroll
      for (int e = 0; e < 8; ++e)
        v[e] = (short)bf16bits(W[(kh * 32 + kg * 8 + e) * 64 + nb * 16 + r]);
      wf[nb][kh] = v;
    }

  const f32x4 zero = {0.f, 0.f, 0.f, 0.f};
#pragma unroll
  for (int nb = 0; nb < 4; ++nb) {
    f32x4 acc = __builtin_amdgcn_mfma_f32_16x16x32_bf16(xa[0], wf[nb][0], zero, 0, 0, 0);
    acc = __builtin_amdgcn_mfma_f32_16x16x32_bf16(xa[1], wf[nb][1], acc, 0, 0, 0);
    float bb = bias[nb * 16 + r];
#pragma unroll
    for (int q = 0; q < 4; ++q) {
      float z = acc[q] + bb;
      // JAX default gelu (approximate=True, tanh form)
      float t = tanhf(0.7978845608028654f * (z + 0.044715f * z * z * z));
      float g = 0.5f * z * (1.0f + t);
      hb[(size_t)(row0 + kg * 4 + q) * 64 + nb * 16 + r] = bf16bits(g);
    }
  }
}

// ---------------- pair kernel (32x32x16 MFMA, fused finish) ----------------
// 1200 blocks = 300 pairs x (2 row-halves x 2 col-halves). Block =
// 256 A-rows x 256 B-rows; B half (32KB) staged once to LDS (swizzled).
// Wave = 64 A-rows (2 row-tiles of 32) x 256 cols (8 cn of 32).
// Block sum -> device atomicAdd(sums[p]); completion forced via return-
// value consume; 4th block (cnt) computes log and writes mirror cells.
__global__ __launch_bounds__(256) void pair_kernel(
    const u16* __restrict__ hb, u32* __restrict__ sums_cnt,
    float* __restrict__ out) {
  __shared__ char smem[32768];

  float* sums = (float*)sums_cnt;        // [300]
  u32* cnt = sums_cnt + 300;             // [300]

  int idx = blockIdx.x;
  int p = idx >> 2;
  int tile = idx & 3;
  int rh = tile >> 1;          // row half of A (256 rows)
  int ch = tile & 1;           // col half of B (256 rows)
  // decode triangular index p -> (i,j), i<=j
  int i = 0, rem = p;
  while (rem >= 24 - i) { rem -= 24 - i; ++i; }
  int j = i + rem;

  const u16* Ap = hb + (size_t)i * 512 * 64;
  const char* Bbytes =
      (const char*)(hb + (size_t)j * 512 * 64) + (size_t)ch * 256 * 128;

  int wid = threadIdx.x >> 6;
  int lane = threadIdx.x & 63;
  int r32 = lane & 31;      // row-in-32-fragment
  int kg2 = lane >> 5;      // k-group (8 contiguous bf16 = 16B), K=16/mfma
  int row0 = rh * 256 + wid * 64;

  // A fragments: 64 rows = 2 tiles of 32, K=64 = 4 kf slices of 16.
  bf16x8 a[2][4];
#pragma unroll
  for (int t = 0; t < 2; ++t)
#pragma unroll
    for (int kf = 0; kf < 4; ++kf)
      a[t][kf] = *reinterpret_cast<const bf16x8*>(
          Ap + (size_t)(row0 + t * 32 + r32) * 64 + kf * 16 + kg2 * 8);

  // Stage B half: 32KB = 4 waves x 8 calls x 1KB. LDS dest linear;
  // global source pre-swizzled with the involution the reads use.
#pragma unroll
  for (int c = 0; c < 8; ++c) {
    int obase = (wid * 8 + c) * 1024;
    int o = obase + lane * 16;
    int src = o ^ (((o >> 7) & 7) << 4);
    __builtin_amdgcn_global_load_lds(
        (const __attribute__((address_space(1))) void*)(Bbytes + src),
        (__attribute__((address_space(3))) void*)(smem + obase), 16, 0, 0);
  }

  // Per-lane LDS read offsets (swizzle bits depend only on lane).
  int swz = (r32 & 7) << 4;
  int boff[4];
#pragma unroll
  for (int kf = 0; kf < 4; ++kf)
    boff[kf] = r32 * 128 + ((kf * 32 + kg2 * 16) ^ swz);

  __syncthreads();

  float s0 = 0.f, s1 = 0.f, s2 = 0.f, s3 = 0.f;
  const f32x16 zero16 = {0.f, 0.f, 0.f, 0.f, 0.f, 0.f, 0.f, 0.f,
                         0.f, 0.f, 0.f, 0.f, 0.f, 0.f, 0.f, 0.f};

#pragma unroll
  for (int cn = 0; cn < 8; ++cn) {
    const char* bp = smem + cn * 4096;   // 32 rows x 128 B per cn
    bf16x8 b0 = *reinterpret_cast<const bf16x8*>(bp + boff[0]);
    bf16x8 b1 = *reinterpret_cast<const bf16x8*>(bp + boff[1]);
    bf16x8 b2 = *reinterpret_cast<const bf16x8*>(bp + boff[2]);
    bf16x8 b3 = *reinterpret_cast<const bf16x8*>(bp + boff[3]);
#pragma unroll
    for (int t = 0; t < 2; ++t) {
      f32x16 acc = __builtin_amdgcn_mfma_f32_32x32x16_bf16(a[t][0], b0, zero16, 0, 0, 0);
      acc = __builtin_amdgcn_mfma_f32_32x32x16_bf16(a[t][1], b1, acc, 0, 0, 0);
      acc = __builtin_amdgcn_mfma_f32_32x32x16_bf16(a[t][2], b2, acc, 0, 0, 0);
      acc = __builtin_amdgcn_mfma_f32_32x32x16_bf16(a[t][3], b3, acc, 0, 0, 0);
#pragma unroll
      for (int q = 0; q < 16; q += 4) {
        s0 += fast_exp(acc[q + 0]);
        s1 += fast_exp(acc[q + 1]);
        s2 += fast_exp(acc[q + 2]);
        s3 += fast_exp(acc[q + 3]);
      }
    }
  }
  float sum = (s0 + s1) + (s2 + s3);
#pragma unroll
  for (int off = 32; off >= 1; off >>= 1) sum += __shfl_xor(sum, off, 64);

  // Block reduction via LDS (alias smem AFTER all B reads are done).
  __syncthreads();
  if (lane == 0) *reinterpret_cast<float*>(smem + wid * 4) = sum;
  __syncthreads();

  if (threadIdx.x == 0) {
    const float* sf = reinterpret_cast<const float*>(smem);
    float bsum = (sf[0] + sf[1]) + (sf[2] + sf[3]);
    // Device-scope RMW at the L2 coherence point. Consuming the return
    // value forces s_waitcnt vmcnt(0) (add COMPLETED) before the cnt
    // atomic below is issued -> no __threadfence needed.
    float old = atomicAdd(&sums[p], bsum);
    asm volatile("" ::"v"(old));   // pin completion-order, zero cost
    u32 n = atomicAdd(&cnt[p], 1u);
    if (n == 3u) {
      // All 4 sums-adds completed before their cnt-adds; observing the
      // 4th cnt-add implies the full total is in sums[p].
      float total = atomicAdd(&sums[p], 0.0f);
      float sc = logf(total);
      out[i * 24 + j] = sc;
      if (i != j) out[j * 24 + i] = sc;
    }
  }
}

extern "C" void kernel_launch(void* const* d_in, const int* in_sizes, int n_in,
                              void* d_out, int out_size, void* d_ws,
                              size_t ws_size, hipStream_t stream) {
  const float* x = (const float*)d_in[0];
  const float* W = (const float*)d_in[1];
  const float* bias = (const float*)d_in[2];
  float* out = (float*)d_out;

  u16* hb = (u16*)d_ws;                      // 12288*64 bf16 = 1.50 MiB
  u32* sums_cnt = (u32*)(hb + 12288 * 64);   // 300 f32 sums + 300 u32 cnt

  encode_kernel<<<192, 256, 0, stream>>>(x, W, bias, hb, sums_cnt);
  pair_kernel<<<1200, 256, 0, stream>>>(hb, sums_cnt, out);
}

// Round 18
// 25.518 us; speedup vs baseline: 1.0337x; 1.0337x over previous
//
#include <hip/hip_runtime.h>
#include <hip/hip_bf16.h>

// Problem: B=24, L=512, D=64, H=64
//   h = gelu(x @ W + b); S = h_i h_j^T per pair; scores = logsumexp(S).
// 300 unique (i<=j) pairs, mirrored at the end.
//
// R18 = exact revert to R15 (best verified: 25.5us). Subsequent
// experiments all regressed: setprio (R16, null/-0.3), fence-free
// atomic fused finisher (R17, +0.9), threadfence finisher (R13, +25),
// cooperative fusion (R11, +100). Structure:
//  - encode: MFMA (16x16x32) gelu(x@W+b) -> single bf16 hb array
//  - pair: 1200 blocks = 300 pairs x 2x2; 32KB swizzled LDS B-staging
//    (pre-swizzled global source + swizzled ds_read, 0 bank conflicts);
//    wave = 64 rows x 256 cols; mfma_f32_32x32x16 4-chain over K=64;
//    Schraudolph e^x (log2e folded): fma+cvt, no TRANS pipe;
//    per-wave partials to unique slots (no atomics, no memset).
//  - finish: 576 threads sum 16 partials, log, mirror.
// Ceiling ledger: ~8-10us fixed graph+boundary (the boundary IS the XCD
// L2 flush that publishes hb - fusion is coherence-blocked), pair ~11.5
// vs ~5 pipe floor (residual = wave-scheduler stall; six structural
// levers each moved <=1us), encode ~2.5, finish ~1.

typedef unsigned short u16;
typedef __attribute__((ext_vector_type(8))) short bf16x8;
typedef __attribute__((ext_vector_type(4))) float f32x4;
typedef __attribute__((ext_vector_type(16))) float f32x16;

static __device__ __forceinline__ u16 bf16bits(float f) {
  __hip_bfloat16 h = __float2bfloat16(f);
  return *reinterpret_cast<u16*>(&h);
}

// Schraudolph fast e^x (log2e folded into the multiplier):
// e^x ~= as_float((int)(x*log2e*2^23 + (127*2^23 - 254615))).
// Valid |x| < 87; rel err <= 3.04%  ->  <=0.03 absolute on log-scores.
static __device__ __forceinline__ float fast_exp(float x) {
  int i = (int)fmaf(x, 12102203.0f, 1065098601.0f);
  return __int_as_float(i);
}

// ---------------- encoder: h = gelu(x@W+b) via MFMA -----------------------
__global__ __launch_bounds__(256) void encode_kernel(
    const float* __restrict__ x, const float* __restrict__ W,
    const float* __restrict__ bias, u16* __restrict__ hb) {
  int lane = threadIdx.x & 63;
  int wid = threadIdx.x >> 6;
  int row0 = (blockIdx.x * 4 + wid) * 16;      // 12288 rows / 16 = 768 waves
  int r = lane & 15;
  int kg = lane >> 4;

  bf16x8 xa[2];
#pragma unroll
  for (int kh = 0; kh < 2; ++kh) {
    const float* xp = x + (size_t)(row0 + r) * 64 + kh * 32 + kg * 8;
    bf16x8 v;
#pragma unroll
    for (int e = 0; e < 8; ++e) v[e] = (short)bf16bits(xp[e]);
    xa[kh] = v;
  }

  bf16x8 wf[4][2];
#pragma unroll
  for (int nb = 0; nb < 4; ++nb)
#pragma unroll
    for (int kh = 0; kh < 2; ++kh) {
      bf16x8 v;
#pragma unroll
      for (int e = 0; e < 8; ++e)
        v[e] = (short)bf16bits(W[(kh * 32 + kg * 8 + e) * 64 + nb * 16 + r]);
      wf[nb][kh] = v;
    }

  const f32x4 zero = {0.f, 0.f, 0.f, 0.f};
#pragma unroll
  for (int nb = 0; nb < 4; ++nb) {
    f32x4 acc = __builtin_amdgcn_mfma_f32_16x16x32_bf16(xa[0], wf[nb][0], zero, 0, 0, 0);
    acc = __builtin_amdgcn_mfma_f32_16x16x32_bf16(xa[1], wf[nb][1], acc, 0, 0, 0);
    float bb = bias[nb * 16 + r];
#pragma unroll
    for (int q = 0; q < 4; ++q) {
      float z = acc[q] + bb;
      // JAX default gelu (approximate=True, tanh form)
      float t = tanhf(0.7978845608028654f * (z + 0.044715f * z * z * z));
      float g = 0.5f * z * (1.0f + t);
      hb[(size_t)(row0 + kg * 4 + q) * 64 + nb * 16 + r] = bf16bits(g);
    }
  }
}

// ---------------- pair kernel (32x32x16 MFMA) ------------------------------
// 1200 blocks = 300 pairs x (2 row-halves x 2 col-halves). Block =
// 256 A-rows x 256 B-rows; B half (32KB) staged once to LDS (swizzled).
// Wave = 64 A-rows (2 row-tiles of 32, a[2][4] frags) x 256 cols
// (8 cn of 32). Per cn: 4 ds_read_b128 + 2x (4-chain MFMA + 16 exps).
__global__ __launch_bounds__(256) void pair_kernel(
    const u16* __restrict__ hb, float* __restrict__ part) {
  __shared__ char smem[32768];

  int idx = blockIdx.x;
  int p = idx >> 2;
  int tile = idx & 3;
  int rh = tile >> 1;          // row half of A (256 rows)
  int ch = tile & 1;           // col half of B (256 rows)
  // decode triangular index p -> (i,j), i<=j
  int i = 0, rem = p;
  while (rem >= 24 - i) { rem -= 24 - i; ++i; }
  int j = i + rem;

  const u16* Ap = hb + (size_t)i * 512 * 64;
  const char* Bbytes =
      (const char*)(hb + (size_t)j * 512 * 64) + (size_t)ch * 256 * 128;

  int wid = threadIdx.x >> 6;
  int lane = threadIdx.x & 63;
  int r32 = lane & 31;      // row-in-32-fragment
  int kg2 = lane >> 5;      // k-group (8 contiguous bf16 = 16B), K=16/mfma
  int row0 = rh * 256 + wid * 64;

  // A fragments: 64 rows = 2 tiles of 32, K=64 = 4 kf slices of 16.
  // lane holds A[row = t*32 + r32][k = kf*16 + kg2*8 + e].
  bf16x8 a[2][4];
#pragma unroll
  for (int t = 0; t < 2; ++t)
#pragma unroll
    for (int kf = 0; kf < 4; ++kf)
      a[t][kf] = *reinterpret_cast<const bf16x8*>(
          Ap + (size_t)(row0 + t * 32 + r32) * 64 + kf * 16 + kg2 * 8);

  // Stage B half: 32KB = 4 waves x 8 calls x 1KB. LDS dest linear;
  // global source pre-swizzled with the involution the reads use.
#pragma unroll
  for (int c = 0; c < 8; ++c) {
    int obase = (wid * 8 + c) * 1024;
    int o = obase + lane * 16;
    int src = o ^ (((o >> 7) & 7) << 4);
    __builtin_amdgcn_global_load_lds(
        (const __attribute__((address_space(1))) void*)(Bbytes + src),
        (__attribute__((address_space(3))) void*)(smem + obase), 16, 0, 0);
  }

  // Per-lane LDS read offsets (swizzle bits depend only on lane).
  // B row (= S column) cn*32 + r32; byte col (kf*32 + kg2*16) ^ swz.
  int swz = (r32 & 7) << 4;
  int boff[4];
#pragma unroll
  for (int kf = 0; kf < 4; ++kf)
    boff[kf] = r32 * 128 + ((kf * 32 + kg2 * 16) ^ swz);

  __syncthreads();

  float s0 = 0.f, s1 = 0.f, s2 = 0.f, s3 = 0.f;
  const f32x16 zero16 = {0.f, 0.f, 0.f, 0.f, 0.f, 0.f, 0.f, 0.f,
                         0.f, 0.f, 0.f, 0.f, 0.f, 0.f, 0.f, 0.f};

#pragma unroll
  for (int cn = 0; cn < 8; ++cn) {
    const char* bp = smem + cn * 4096;   // 32 rows x 128 B per cn
    bf16x8 b0 = *reinterpret_cast<const bf16x8*>(bp + boff[0]);
    bf16x8 b1 = *reinterpret_cast<const bf16x8*>(bp + boff[1]);
    bf16x8 b2 = *reinterpret_cast<const bf16x8*>(bp + boff[2]);
    bf16x8 b3 = *reinterpret_cast<const bf16x8*>(bp + boff[3]);
#pragma unroll
    for (int t = 0; t < 2; ++t) {
      f32x16 acc = __builtin_amdgcn_mfma_f32_32x32x16_bf16(a[t][0], b0, zero16, 0, 0, 0);
      acc = __builtin_amdgcn_mfma_f32_32x32x16_bf16(a[t][1], b1, acc, 0, 0, 0);
      acc = __builtin_amdgcn_mfma_f32_32x32x16_bf16(a[t][2], b2, acc, 0, 0, 0);
      acc = __builtin_amdgcn_mfma_f32_32x32x16_bf16(a[t][3], b3, acc, 0, 0, 0);
#pragma unroll
      for (int q = 0; q < 16; q += 4) {
        s0 += fast_exp(acc[q + 0]);
        s1 += fast_exp(acc[q + 1]);
        s2 += fast_exp(acc[q + 2]);
        s3 += fast_exp(acc[q + 3]);
      }
    }
  }
  float sum = (s0 + s1) + (s2 + s3);
#pragma unroll
  for (int off = 32; off >= 1; off >>= 1) sum += __shfl_xor(sum, off, 64);
  if (lane == 0) part[idx * 4 + wid] = sum;
}

// ---------------- finalize: sum 16 partials per pair, log, mirror ---------
__global__ void finish_kernel(const float* __restrict__ part,
                              float* __restrict__ out) {
  int t = threadIdx.x + blockIdx.x * blockDim.x;
  if (t >= 576) return;
  int i = t / 24, j = t % 24;
  int ii = i < j ? i : j, jj = i < j ? j : i;
  int p = ii * 24 - ii * (ii - 1) / 2 + (jj - ii);
  const f32x4* pv = reinterpret_cast<const f32x4*>(part + p * 16);
  float s = 0.f;
#pragma unroll
  for (int q = 0; q < 4; ++q) {
    f32x4 v = pv[q];
    s += (v[0] + v[1]) + (v[2] + v[3]);
  }
  out[t] = logf(s);
}

extern "C" void kernel_launch(void* const* d_in, const int* in_sizes, int n_in,
                              void* d_out, int out_size, void* d_ws,
                              size_t ws_size, hipStream_t stream) {
  const float* x = (const float*)d_in[0];
  const float* W = (const float*)d_in[1];
  const float* bias = (const float*)d_in[2];
  float* out = (float*)d_out;

  u16* hb = (u16*)d_ws;                      // 12288*64 bf16 = 1.50 MiB
  float* part = (float*)(hb + 12288 * 64);   // 1200 * 4 = 4800 f32

  encode_kernel<<<192, 256, 0, stream>>>(x, W, bias, hb);
  pair_kernel<<<1200, 256, 0, stream>>>(hb, part);
  finish_kernel<<<9, 64, 0, stream>>>(part, out);
}